// Round 14
// baseline (164.931 us; speedup 1.0000x reference)
//
#include <hip/hip_runtime.h>

typedef __bf16 bf16x8 __attribute__((ext_vector_type(8)));
typedef float f32x4 __attribute__((ext_vector_type(4)));
typedef float f32x16 __attribute__((ext_vector_type(16)));
typedef unsigned short u16x8 __attribute__((ext_vector_type(8)));
typedef unsigned short u16x4 __attribute__((ext_vector_type(4)));
typedef unsigned u32x4 __attribute__((ext_vector_type(4)));

#define BB 4
#define TT 2048
#define CC 1024
#define HH 16
#define DD 64

__device__ __forceinline__ unsigned short f2bf(float f){
  unsigned u = __builtin_bit_cast(unsigned, f);
  u += 0x7FFFu + ((u >> 16) & 1u);
  return (unsigned short)(u >> 16);
}
__device__ __forceinline__ bf16x8 as_bf(u16x8 v){ return __builtin_bit_cast(bf16x8, v); }
__device__ __forceinline__ unsigned cvt_pk(float lo, float hi){
  unsigned r; asm("v_cvt_pk_bf16_f32 %0, %1, %2" : "=v"(r) : "v"(lo), "v"(hi)); return r;
}
__device__ __forceinline__ void pl32swap(unsigned &a, unsigned &b){
  asm("v_permlane32_swap_b32 %0, %1" : "+v"(a), "+v"(b));
}
__device__ __forceinline__ float ex2(float x){
#if __has_builtin(__builtin_amdgcn_exp2f)
  return __builtin_amdgcn_exp2f(x);
#else
  return __expf(x * 0.6931471805599453f);
#endif
}

// all 5 fp32->bf16 conversions in one launch
__global__ __launch_bounds__(256) void cvt_all(const float* __restrict__ x,
                                               const float* __restrict__ Wk,
                                               const float* __restrict__ Wq,
                                               const float* __restrict__ Wv,
                                               const float* __restrict__ Wp,
                                               unsigned short* __restrict__ xb,
                                               unsigned short* __restrict__ wb){
  const int i = blockIdx.x * 256 + threadIdx.x;           // one float4 per thread
  constexpr int EX = (BB*TT*CC)/4;                        // 2,097,152
  const float* src; unsigned short* dst; int off;
  if (i < EX){ src = x; dst = xb; off = i; }
  else {
    const int j = i - EX;
    const int wsel = j >> 18;                             // Wn/4 = 2^18
    off = j & 262143;
    src = (wsel==0) ? Wk : (wsel==1) ? Wq : (wsel==2) ? Wv : Wp;
    dst = wb + ((size_t)wsel << 20);                      // Wn = 2^20
  }
  const float4 f = ((const float4*)src)[off];
  u16x4 o; o.x = f2bf(f.x); o.y = f2bf(f.y); o.z = f2bf(f.z); o.w = f2bf(f.w);
  ((u16x4*)dst)[off] = o;
}

// ---------------- 256x128 QKV GEMM, 32x32x16 MFMA, 2 blocks/CU overlap ----------------
// C = A @ B^T, A: 8192x1024 bf16, B: 3072x1024 bf16 ([Wk;Wq;Wv]).
// 4 waves (2Mx2N), wave tile 128x64 = 4x2 of 32x32. Single-buffer 2-barrier flow
// (proven m97 class); overlap comes from 2 co-resident blocks/CU (48 KB LDS, <=256 VGPR).
// Grid 24x32 = 768 WGs = 3 blocks/CU total, no tail. tsel 0 -> K (o0), 1 -> Q
// (o1, *log2e/8), 2 -> V transposed (o2=Vt, XOR k-chunk swizzle).
__global__ __launch_bounds__(256, 2) void gemmqkv(const unsigned short* __restrict__ A,
                                                  const unsigned short* __restrict__ Bm,
                                                  void* __restrict__ o0, void* __restrict__ o1,
                                                  void* __restrict__ o2){
  constexpr int K = 1024;
  __shared__ __align__(16) unsigned short As[256*64];
  __shared__ __align__(16) unsigned short Bs[128*64];
  const int tid = threadIdx.x;
  const int flat = blockIdx.y * 24 + blockIdx.x;          // 32 x 24 = 768
  const int swz = (flat & 7) * 96 + (flat >> 3);          // bijective (768%8==0)
  const int n0 = (swz % 24) * 128;
  const int m0 = (swz / 24) * 256;
  const int w = tid >> 6, lane = tid & 63, l31 = lane & 31, hi = lane >> 5;
  const int wm = (w >> 1) * 128, wn = (w & 1) * 64;
  const int tsel = n0 >> 10;                              // block-uniform

  f32x16 acc[4][2] = {};

  for (int k0 = 0; k0 < K; k0 += 64){
    #pragma unroll
    for (int i = 0; i < 8; ++i){                          // A: 256x64
      const int p = i*256 + tid;
      const int r = p >> 3, c = p & 7;
      const int gc = c ^ (r & 7);
      __builtin_amdgcn_global_load_lds(
        (const __attribute__((address_space(1))) void*)(A + (size_t)(m0 + r)*K + k0 + gc*8),
        (__attribute__((address_space(3))) void*)(As + p*8), 16, 0, 0);
    }
    #pragma unroll
    for (int i = 0; i < 4; ++i){                          // B: 128x64
      const int p = i*256 + tid;
      const int r = p >> 3, c = p & 7;
      const int gc = c ^ (r & 7);
      __builtin_amdgcn_global_load_lds(
        (const __attribute__((address_space(1))) void*)(Bm + (size_t)(n0 + r)*K + k0 + gc*8),
        (__attribute__((address_space(3))) void*)(Bs + p*8), 16, 0, 0);
    }
    __syncthreads();

    #pragma unroll
    for (int ks = 0; ks < 4; ++ks){                       // 16-k steps
      bf16x8 bf2[2];
      #pragma unroll
      for (int nb = 0; nb < 2; ++nb){
        const int R = wn + nb*32 + l31;
        const int cc = (2*ks + hi) ^ (R & 7);
        bf2[nb] = as_bf(*(const u16x8*)(Bs + R*64 + cc*8));
      }
      __builtin_amdgcn_s_setprio(1);
      #pragma unroll
      for (int mb = 0; mb < 4; ++mb){
        const int R = wm + mb*32 + l31;
        const int cc = (2*ks + hi) ^ (R & 7);
        bf16x8 a = as_bf(*(const u16x8*)(As + R*64 + cc*8));
        acc[mb][0] = __builtin_amdgcn_mfma_f32_32x32x16_bf16(a, bf2[0], acc[mb][0], 0, 0, 0);
        acc[mb][1] = __builtin_amdgcn_mfma_f32_32x32x16_bf16(a, bf2[1], acc[mb][1], 0, 0, 0);
      }
      __builtin_amdgcn_s_setprio(0);
    }
    __syncthreads();
  }

  if (tsel == 2){
    // V epilogue: write transposed to Vt [B*H][D][T] with XOR k-chunk swizzle.
    // 32x32 C-layout: col = l31, row = (reg&3) + 8*(reg>>2) + 4*hi -> regs 4q..4q+3
    // give 4 consecutive t at t&7 = 4*hi -> u16x4 run inside one 8-chunk.
    const int bq = m0 >> 11;
    const int t0b = m0 & 2047;
    unsigned short* vt = (unsigned short*)o2;
    #pragma unroll
    for (int nb = 0; nb < 2; ++nb){
      const int cg = (n0 & 1023) + wn + nb*32 + l31;      // channel 0..1023
      const int h = cg >> 6, d = cg & 63;
      unsigned short* base = vt + ((size_t)(bq*HH + h)*DD + d)*TT;
      #pragma unroll
      for (int mb = 0; mb < 4; ++mb)
        #pragma unroll
        for (int q = 0; q < 4; ++q){
          const int t = t0b + wm + mb*32 + 8*q + 4*hi;
          const int kt = t >> 6;
          const int cch = ((t >> 3) & 7) ^ (d & 7);
          u16x4 pv;
          pv.x = f2bf(acc[mb][nb][4*q+0]); pv.y = f2bf(acc[mb][nb][4*q+1]);
          pv.z = f2bf(acc[mb][nb][4*q+2]); pv.w = f2bf(acc[mb][nb][4*q+3]);
          *(u16x4*)(base + (size_t)kt*64 + cch*8 + (t & 7)) = pv;
        }
    }
    return;
  }

  const float sc = (tsel == 1) ? 0.18033688011112042f : 1.0f;  // log2(e)/8
  unsigned short* outb = (unsigned short*)(tsel == 0 ? o0 : o1);
  #pragma unroll
  for (int mb = 0; mb < 4; ++mb)
    #pragma unroll
    for (int nb = 0; nb < 2; ++nb){
      const int col = (n0 & 1023) + wn + nb*32 + l31;
      #pragma unroll
      for (int r = 0; r < 16; ++r){
        const int row = m0 + wm + mb*32 + (r & 3) + 8*(r >> 2) + 4*hi;
        outb[(size_t)row*1024 + col] = f2bf(acc[mb][nb][r] * sc);
      }
    }
}

// ---------------- proven 128^2 GEMM (used for output projection) ----------------
template<int NX>
__global__ __launch_bounds__(256) void gemm128(const unsigned short* __restrict__ A,
                                               const unsigned short* __restrict__ Bm,
                                               float* __restrict__ o0){
  constexpr int K = 1024;
  constexpr int NWG = NX * 64;
  __shared__ __align__(16) unsigned short As[128*64];
  __shared__ __align__(16) unsigned short Bs[128*64];
  const int tid = threadIdx.x;
  const int flat = blockIdx.y * NX + blockIdx.x;
  const int swz = (flat & 7) * (NWG / 8) + (flat >> 3);
  const int n0 = (swz % NX) * 128;
  const int m0 = (swz / NX) * 128;
  const int w = tid >> 6, lane = tid & 63, l15 = lane & 15, g = lane >> 4;
  const int wm = (w >> 1) * 64, wn = (w & 1) * 64;

  f32x4 acc[4][4] = {};

  for (int k0 = 0; k0 < K; k0 += 64){
    #pragma unroll
    for (int i = 0; i < 4; ++i){
      const int p = i*256 + tid;
      const int r = p >> 3, c = p & 7;
      const int gc = c ^ (r & 7);
      __builtin_amdgcn_global_load_lds(
        (const __attribute__((address_space(1))) void*)(A + (size_t)(m0 + r)*K + k0 + gc*8),
        (__attribute__((address_space(3))) void*)(As + p*8), 16, 0, 0);
    }
    #pragma unroll
    for (int i = 0; i < 4; ++i){
      const int p = i*256 + tid;
      const int r = p >> 3, c = p & 7;
      const int gc = c ^ (r & 7);
      __builtin_amdgcn_global_load_lds(
        (const __attribute__((address_space(1))) void*)(Bm + (size_t)(n0 + r)*K + k0 + gc*8),
        (__attribute__((address_space(3))) void*)(Bs + p*8), 16, 0, 0);
    }
    __syncthreads();

    bf16x8 af[2][4], bfr[2][4];
    #pragma unroll
    for (int ks = 0; ks < 2; ++ks){
      #pragma unroll
      for (int m = 0; m < 4; ++m){
        const int R = wm + m*16 + l15;
        const int c = (ks*4 + g) ^ (R & 7);
        af[ks][m] = as_bf(*(const u16x8*)(As + R*64 + c*8));
      }
      #pragma unroll
      for (int n = 0; n < 4; ++n){
        const int R = wn + n*16 + l15;
        const int c = (ks*4 + g) ^ (R & 7);
        bfr[ks][n] = as_bf(*(const u16x8*)(Bs + R*64 + c*8));
      }
    }
    #pragma unroll
    for (int ks = 0; ks < 2; ++ks)
      #pragma unroll
      for (int m = 0; m < 4; ++m)
        #pragma unroll
        for (int n = 0; n < 4; ++n)
          acc[m][n] = __builtin_amdgcn_mfma_f32_16x16x32_bf16(af[ks][m], bfr[ks][n], acc[m][n], 0, 0, 0);
    __syncthreads();
  }

  #pragma unroll
  for (int m = 0; m < 4; ++m)
    #pragma unroll
    for (int n = 0; n < 4; ++n)
      #pragma unroll
      for (int r = 0; r < 4; ++r){
        const int row = m0 + wm + m*16 + g*4 + r;
        const int col = n0 + wn + n*16 + l15;
        o0[(size_t)row*1024 + col] = acc[m][n][r];
      }
}

// Causal flash attention, swapped-QK 32x32, 8 waves x 32 q-rows = 256 q-rows/block.
// R6-proven: 3-buffer ring, counted vmcnt(2), balanced strip pairing.
__global__ __launch_bounds__(512, 4) void attn2(const unsigned short* __restrict__ Q,
                                                const unsigned short* __restrict__ Km,
                                                const unsigned short* __restrict__ Vt,
                                                unsigned short* __restrict__ Y){
  __shared__ __align__(16) unsigned short Ks[3][64*64];
  __shared__ __align__(16) unsigned short Vs[3][64*64];
  const int bh = blockIdx.x, b = bh >> 4, h = bh & 15;
  const int yq = blockIdx.y;
  const int qt = (yq < 4) ? (7 - yq) : (yq - 4);
  const int tid = threadIdx.x;
  const int w = tid >> 6, lane = tid & 63, l31 = lane & 31, hi = lane >> 5;
  const int q0 = qt * 256;
  const int wq0 = q0 + w * 32;
  const int wqmax = wq0 + 31;
  const int nkt = 4 * qt + 4;
  const int qg = wq0 + l31;

  const unsigned short* Ksrc = Km + (size_t)b*TT*CC + h*DD;
  const unsigned short* Vsrc = Vt + (size_t)bh*DD*TT;

  auto stage = [&](int buf, int kt){
    const int r = tid >> 3, c = tid & 7;
    const int gc = c ^ (r & 7);
    __builtin_amdgcn_global_load_lds(
      (const __attribute__((address_space(1))) void*)(Ksrc + (size_t)(kt*64 + r)*CC + gc*8),
      (__attribute__((address_space(3))) void*)(&Ks[buf][tid*8]), 16, 0, 0);
    __builtin_amdgcn_global_load_lds(
      (const __attribute__((address_space(1))) void*)(Vsrc + (size_t)r*TT + (size_t)kt*64 + c*8),
      (__attribute__((address_space(3))) void*)(&Vs[buf][tid*8]), 16, 0, 0);
  };

  stage(0, 0);

  const unsigned short* qrow = Q + ((size_t)b*TT + wq0 + l31)*CC + h*DD;
  bf16x8 qf[4];
  #pragma unroll
  for (int ds = 0; ds < 4; ++ds)
    qf[ds] = as_bf(*(const u16x8*)(qrow + 16*ds + 8*hi));

  int koff[4];
  #pragma unroll
  for (int ds = 0; ds < 4; ++ds)
    koff[ds] = l31*64 + (((2*ds + hi) ^ (l31 & 7)) * 8);

  float m_ = -1e30f, l_ = 0.f;
  f32x16 y0 = {}, y1 = {};

  int cb = 0;
  for (int t = 0; t < nkt; ++t){
    const int nx = (cb == 2) ? 0 : cb + 1;
    if (t + 1 < nkt){
      stage(nx, t + 1);
      asm volatile("s_waitcnt vmcnt(2)" ::: "memory");
    } else {
      asm volatile("s_waitcnt vmcnt(0)" ::: "memory");
    }
    __builtin_amdgcn_s_barrier();

    if (t*64 <= wqmax){
      const unsigned short* Kp = &Ks[cb][0];
      const unsigned short* Vp = &Vs[cb][0];

      f32x16 s0 = {}, s1 = {};
      __builtin_amdgcn_s_setprio(1);
      #pragma unroll
      for (int ds = 0; ds < 4; ++ds){
        bf16x8 kf0 = as_bf(*(const u16x8*)(Kp + koff[ds]));
        s0 = __builtin_amdgcn_mfma_f32_32x32x16_bf16(kf0, qf[ds], s0, 0, 0, 0);
        bf16x8 kf1 = as_bf(*(const u16x8*)(Kp + koff[ds] + 2048));
        s1 = __builtin_amdgcn_mfma_f32_32x32x16_bf16(kf1, qf[ds], s1, 0, 0, 0);
      }
      __builtin_amdgcn_s_setprio(0);

      if (t*64 + 63 > wq0){
        const int kb0 = t*64;
        #pragma unroll
        for (int r = 0; r < 16; ++r){
          const int kr = (r & 3) + 8*(r >> 2) + 4*hi;
          if (kb0 + kr      > qg) s0[r] = -1e30f;
          if (kb0 + 32 + kr > qg) s1[r] = -1e30f;
        }
      }

      float tm[8];
      #pragma unroll
      for (int r = 0; r < 8; ++r) tm[r] = fmaxf(fmaxf(s0[r], s0[r+8]), fmaxf(s1[r], s1[r+8]));
      #pragma unroll
      for (int r = 0; r < 4; ++r) tm[r] = fmaxf(tm[r], tm[r+4]);
      float pmax = fmaxf(fmaxf(tm[0], tm[2]), fmaxf(tm[1], tm[3]));
      pmax = fmaxf(pmax, __shfl_xor(pmax, 32));

      if (!__all(pmax <= m_ + 8.f)){
        const float mnew = fmaxf(m_, pmax);
        const float alpha = ex2(m_ - mnew);
        l_ *= alpha;
        #pragma unroll
        for (int r = 0; r < 16; ++r){
          const float ar = __shfl(alpha, (r & 3) + 8*(r >> 2) + 4*hi);
          y0[r] *= ar; y1[r] *= ar;
        }
        m_ = mnew;
      }

      #pragma unroll
      for (int r = 0; r < 16; ++r) s0[r] = ex2(s0[r] - m_);
      #pragma unroll
      for (int r = 0; r < 16; ++r) s1[r] = ex2(s1[r] - m_);
      float ts[8];
      #pragma unroll
      for (int r = 0; r < 8; ++r) ts[r] = (s0[r] + s0[r+8]) + (s1[r] + s1[r+8]);
      #pragma unroll
      for (int r = 0; r < 4; ++r) ts[r] += ts[r+4];
      float rs = (ts[0] + ts[2]) + (ts[1] + ts[3]);
      rs += __shfl_xor(rs, 32);
      l_ += rs;

      __builtin_amdgcn_s_setprio(1);
      #pragma unroll
      for (int m = 0; m < 4; ++m){
        const f32x16 c = (m < 2) ? s0 : s1;
        const int bx = (m & 1) * 8;
        unsigned A0 = cvt_pk(c[bx+0], c[bx+1]);
        unsigned B0 = cvt_pk(c[bx+4], c[bx+5]);
        pl32swap(A0, B0);
        unsigned A1 = cvt_pk(c[bx+2], c[bx+3]);
        unsigned B1 = cvt_pk(c[bx+6], c[bx+7]);
        pl32swap(A1, B1);
        u32x4 pw; pw.x = A0; pw.y = A1; pw.z = B0; pw.w = B1;
        const bf16x8 pa = __builtin_bit_cast(bf16x8, pw);
        bf16x8 vf0 = as_bf(*(const u16x8*)(Vp + koff[m]));
        y0 = __builtin_amdgcn_mfma_f32_32x32x16_bf16(pa, vf0, y0, 0, 0, 0);
        bf16x8 vf1 = as_bf(*(const u16x8*)(Vp + koff[m] + 2048));
        y1 = __builtin_amdgcn_mfma_f32_32x32x16_bf16(pa, vf1, y1, 0, 0, 0);
      }
      __builtin_amdgcn_s_setprio(0);
    }
    cb = nx;
  }

  const float linv = 1.f / l_;
  #pragma unroll
  for (int r = 0; r < 16; ++r){
    const int qlr = (r & 3) + 8*(r >> 2) + 4*hi;
    const float lr = __shfl(linv, qlr);
    unsigned short* yp = Y + ((size_t)b*TT + wq0 + qlr)*CC + h*DD + l31;
    yp[0]  = f2bf(y0[r] * lr);
    yp[32] = f2bf(y1[r] * lr);
  }
}

extern "C" void kernel_launch(void* const* d_in, const int* in_sizes, int n_in,
                              void* d_out, int out_size, void* d_ws, size_t ws_size,
                              hipStream_t stream){
  const float* x  = (const float*)d_in[0];
  const float* Wk = (const float*)d_in[1];
  const float* Wq = (const float*)d_in[2];
  const float* Wv = (const float*)d_in[3];
  const float* Wp = (const float*)d_in[4];

  const size_t E  = (size_t)BB*TT*CC;
  const size_t Wn = (size_t)CC*CC;
  unsigned short* ws  = (unsigned short*)d_ws;
  unsigned short* xb  = ws;                 // reused as yb after attention
  unsigned short* wkb = xb  + E;            // wkb,wqb,wvb contiguous = B[3072][1024]
  unsigned short* wqb = wkb + Wn;
  unsigned short* wvb = wqb + Wn;
  unsigned short* wpb = wvb + Wn;
  unsigned short* qb  = wpb + Wn;
  unsigned short* kb  = qb  + E;
  unsigned short* vt  = kb  + E;            // V written transposed by QKV GEMM

  (void)wqb; (void)wvb;

  cvt_all<<<12288, 256, 0, stream>>>(x, Wk, Wq, Wv, Wp, xb, wkb);

  // fused QKV at 256x128 / 32x32 MFMA: B = [Wk; Wq; Wv] -> kb, qb (scaled), vt
  gemmqkv<<<dim3(24, 32), 256, 0, stream>>>(xb, wkb, kb, qb, vt);

  unsigned short* yb = xb;
  attn2<<<dim3(BB*HH, TT/256), 512, 0, stream>>>(qb, kb, vt, yb);

  gemm128<8><<<dim3(8, 64), 256, 0, stream>>>(yb, wpb, (float*)d_out);
}

// Round 15
// 152.545 us; speedup vs baseline: 1.0812x; 1.0812x over previous
//
#include <hip/hip_runtime.h>

typedef __bf16 bf16x8 __attribute__((ext_vector_type(8)));
typedef float f32x4 __attribute__((ext_vector_type(4)));
typedef float f32x16 __attribute__((ext_vector_type(16)));
typedef unsigned short u16x8 __attribute__((ext_vector_type(8)));
typedef unsigned short u16x4 __attribute__((ext_vector_type(4)));
typedef unsigned u32x4 __attribute__((ext_vector_type(4)));

#define BB 4
#define TT 2048
#define CC 1024
#define HH 16
#define DD 64

__device__ __forceinline__ unsigned short f2bf(float f){
  unsigned u = __builtin_bit_cast(unsigned, f);
  u += 0x7FFFu + ((u >> 16) & 1u);
  return (unsigned short)(u >> 16);
}
__device__ __forceinline__ bf16x8 as_bf(u16x8 v){ return __builtin_bit_cast(bf16x8, v); }
__device__ __forceinline__ unsigned cvt_pk(float lo, float hi){
  unsigned r; asm("v_cvt_pk_bf16_f32 %0, %1, %2" : "=v"(r) : "v"(lo), "v"(hi)); return r;
}
__device__ __forceinline__ void pl32swap(unsigned &a, unsigned &b){
  asm("v_permlane32_swap_b32 %0, %1" : "+v"(a), "+v"(b));
}
__device__ __forceinline__ float ex2(float x){
#if __has_builtin(__builtin_amdgcn_exp2f)
  return __builtin_amdgcn_exp2f(x);
#else
  return __expf(x * 0.6931471805599453f);
#endif
}

// all 5 fp32->bf16 conversions in one launch
__global__ __launch_bounds__(256) void cvt_all(const float* __restrict__ x,
                                               const float* __restrict__ Wk,
                                               const float* __restrict__ Wq,
                                               const float* __restrict__ Wv,
                                               const float* __restrict__ Wp,
                                               unsigned short* __restrict__ xb,
                                               unsigned short* __restrict__ wb){
  const int i = blockIdx.x * 256 + threadIdx.x;           // one float4 per thread
  constexpr int EX = (BB*TT*CC)/4;                        // 2,097,152
  const float* src; unsigned short* dst; int off;
  if (i < EX){ src = x; dst = xb; off = i; }
  else {
    const int j = i - EX;
    const int wsel = j >> 18;                             // Wn/4 = 2^18
    off = j & 262143;
    src = (wsel==0) ? Wk : (wsel==1) ? Wq : (wsel==2) ? Wv : Wp;
    dst = wb + ((size_t)wsel << 20);                      // Wn = 2^20
  }
  const float4 f = ((const float4*)src)[off];
  u16x4 o; o.x = f2bf(f.x); o.y = f2bf(f.y); o.z = f2bf(f.z); o.w = f2bf(f.w);
  ((u16x4*)dst)[off] = o;
}

// ---------------- 256x256 QKV GEMM, read-ahead phase pipeline (best: R12) ----------------
// C = A @ B^T, A: 8192x1024 bf16, B: 3072x1024 bf16 ([Wk;Wq;Wv]).
// 8 waves (2Mx4N), per-wave 128x64. LDS: 4 half-tile slots x (A 256x32 + B 256x32)
// = 128 KB. Phase p (32-k half): stage(p+3) -> vmcnt(8) -> lgkm(0) -> barrier ->
// MFMA(p) [frags pre-read] -> ds_read(p+1). MFMA never waits on fresh lgkm;
// ds_read(p+1) completes under MFMA(p).
// tsel 0 -> K (o0), 1 -> Q (o1, *log2e/8), 2 -> V transposed (o2=Vt).
template<int NX>
__global__ __launch_bounds__(512, 2) void gemm256q(const unsigned short* __restrict__ A,
                                                   const unsigned short* __restrict__ Bm,
                                                   void* __restrict__ o0, void* __restrict__ o1,
                                                   void* __restrict__ o2){
  constexpr int K = 1024;
  constexpr int NWG = NX * 32;
  extern __shared__ unsigned short lds[];                 // 4 x 16384 elems (128 KB)
  const int tid = threadIdx.x;
  const int flat = blockIdx.y * NX + blockIdx.x;
  const int swz = (flat & 7) * (NWG / 8) + (flat >> 3);   // bijective (NWG%8==0)
  const int n0 = (swz % NX) * 256;
  const int m0 = (swz / NX) * 256;
  const int w = tid >> 6, lane = tid & 63, l15 = lane & 15, g = lane >> 4;
  const int wm = (w >> 2) * 128;                          // {0,128}
  const int wn = (w & 3) * 64;                            // {0,64,128,192}
  const int tsel = n0 >> 10;                              // block-uniform

  // staging lane constants (proven 32-k swizzle)
  const int sc_q = lane >> 2;
  const int sc_g = (lane & 3) ^ ((lane >> 3) & 3);
  const int rd_cc = g ^ ((l15 >> 1) & 3);

  // stage half (kt,ks) into slot s: 4 loads/wave (2 A + 2 B)
  auto stage = [&](int s, int kt, int ks){
    #pragma unroll
    for (int j = 0; j < 2; ++j){
      const int wl = j*8 + w;
      const int r = wl*16 + sc_q;
      __builtin_amdgcn_global_load_lds(
        (const __attribute__((address_space(1))) void*)(A + (size_t)(m0 + r)*K + kt*64 + ks*32 + sc_g*8),
        (__attribute__((address_space(3))) void*)(lds + s*16384 + wl*512 + lane*8), 16, 0, 0);
      __builtin_amdgcn_global_load_lds(
        (const __attribute__((address_space(1))) void*)(Bm + (size_t)(n0 + r)*K + kt*64 + ks*32 + sc_g*8),
        (__attribute__((address_space(3))) void*)(lds + s*16384 + 8192 + wl*512 + lane*8), 16, 0, 0);
    }
  };

  int aoff[8], boff[4];
  #pragma unroll
  for (int m = 0; m < 8; ++m) aoff[m] = (wm + m*16 + l15)*32 + rd_cc*8;
  #pragma unroll
  for (int n = 0; n < 4; ++n) boff[n] = 8192 + (wn + n*16 + l15)*32 + rd_cc*8;

  auto dsread = [&](int sbase, bf16x8* af, bf16x8* bfr){
    const unsigned short* base = lds + sbase;
    #pragma unroll
    for (int n = 0; n < 4; ++n) bfr[n] = as_bf(*(const u16x8*)(base + boff[n]));
    #pragma unroll
    for (int m = 0; m < 8; ++m) af[m] = as_bf(*(const u16x8*)(base + aoff[m]));
  };

  f32x4 acc[8][4] = {};
  auto mfma32 = [&](bf16x8* af, bf16x8* bfr){
    __builtin_amdgcn_s_setprio(1);
    #pragma unroll
    for (int m = 0; m < 8; ++m)
      #pragma unroll
      for (int n = 0; n < 4; ++n)
        acc[m][n] = __builtin_amdgcn_mfma_f32_16x16x32_bf16(af[m], bfr[n], acc[m][n], 0, 0, 0);
    __builtin_amdgcn_s_setprio(0);
  };

  bf16x8 afA[8], bfA[4], afB[8], bfB[4];

  // prologue: halves 0,1,2 -> slots 0,1,2; half0 landed -> pre-read set A
  stage(0, 0, 0); stage(1, 0, 1); stage(2, 1, 0);
  asm volatile("s_waitcnt vmcnt(8)" ::: "memory");
  __builtin_amdgcn_s_barrier();
  dsread(0, afA, bfA);

#define PHASE(SSTG, KT, KS, VMC, SRD, AF_U, BF_U, AF_R, BF_R)      \
  do {                                                             \
    if (SSTG >= 0) stage(SSTG, KT, KS);                            \
    asm volatile("s_waitcnt vmcnt(" #VMC ")" ::: "memory");        \
    asm volatile("s_waitcnt lgkmcnt(0)" ::: "memory");             \
    __builtin_amdgcn_s_barrier();                                  \
    __builtin_amdgcn_sched_barrier(0);                             \
    mfma32(AF_U, BF_U);                                            \
    dsread((SRD)*16384, AF_R, BF_R);                               \
  } while (0)

  for (int t = 0; t < 14; t += 2){
    PHASE(3, t+1, 1, 8, 1, afA, bfA, afB, bfB);   // p=2t:   stage half 2t+3, read 2t+1
    PHASE(0, t+2, 0, 8, 2, afB, bfB, afA, bfA);   // p=2t+1: stage half 2t+4, read 2t+2
    PHASE(1, t+2, 1, 8, 3, afA, bfA, afB, bfB);   // p=2t+2: stage half 2t+5, read 2t+3
    PHASE(2, t+3, 0, 8, 0, afB, bfB, afA, bfA);   // p=2t+3: stage half 2t+6, read 2t+4
  }
  // tail: phases 28..31 (tiles 14,15)
  PHASE( 3, 15, 1, 8, 1, afA, bfA, afB, bfB);     // p28: stage half31, read half29
  PHASE(-1,  0, 0, 4, 2, afB, bfB, afA, bfA);     // p29: read half30
  PHASE(-1,  0, 0, 0, 3, afA, bfA, afB, bfB);     // p30: read half31
  asm volatile("s_waitcnt lgkmcnt(0)" ::: "memory");
  __builtin_amdgcn_sched_barrier(0);
  mfma32(afB, bfB);                                // p31
#undef PHASE

  if (tsel == 2){
    // V epilogue: write transposed to Vt [B*H][D][T] with XOR k-chunk swizzle (u16x4 runs).
    const int bq = m0 >> 11;
    const int t0 = m0 & 2047;
    unsigned short* vt = (unsigned short*)o2;
    #pragma unroll
    for (int n = 0; n < 4; ++n){
      const int cg = (n0 & 1023) + wn + n*16 + l15;        // channel 0..1023
      const int h = cg >> 6, d = cg & 63;
      unsigned short* base = vt + ((size_t)(bq*HH + h)*DD + d)*TT;
      #pragma unroll
      for (int m = 0; m < 8; ++m){
        const int t = t0 + wm + m*16 + g*4;
        const int kt = t >> 6;
        const int cch = ((t >> 3) & 7) ^ (d & 7);
        u16x4 pv;
        pv.x = f2bf(acc[m][n][0]); pv.y = f2bf(acc[m][n][1]);
        pv.z = f2bf(acc[m][n][2]); pv.w = f2bf(acc[m][n][3]);
        *(u16x4*)(base + (size_t)kt*64 + cch*8 + (t & 7)) = pv;
      }
    }
    return;
  }

  const float sc = (tsel == 1) ? 0.18033688011112042f : 1.0f;  // log2(e)/8
  unsigned short* outb = (unsigned short*)(tsel == 0 ? o0 : o1);
  #pragma unroll
  for (int m = 0; m < 8; ++m)
    #pragma unroll
    for (int n = 0; n < 4; ++n)
      #pragma unroll
      for (int r = 0; r < 4; ++r){
        const int row = m0 + wm + m*16 + g*4 + r;
        const int col = (n0 & 1023) + wn + n*16 + l15;
        outb[(size_t)row*1024 + col] = f2bf(acc[m][n][r] * sc);
      }
}

// ---------------- proven 128^2 GEMM (used for output projection) ----------------
template<int NX>
__global__ __launch_bounds__(256) void gemm128(const unsigned short* __restrict__ A,
                                               const unsigned short* __restrict__ Bm,
                                               float* __restrict__ o0){
  constexpr int K = 1024;
  constexpr int NWG = NX * 64;
  __shared__ __align__(16) unsigned short As[128*64];
  __shared__ __align__(16) unsigned short Bs[128*64];
  const int tid = threadIdx.x;
  const int flat = blockIdx.y * NX + blockIdx.x;
  const int swz = (flat & 7) * (NWG / 8) + (flat >> 3);
  const int n0 = (swz % NX) * 128;
  const int m0 = (swz / NX) * 128;
  const int w = tid >> 6, lane = tid & 63, l15 = lane & 15, g = lane >> 4;
  const int wm = (w >> 1) * 64, wn = (w & 1) * 64;

  f32x4 acc[4][4] = {};

  for (int k0 = 0; k0 < K; k0 += 64){
    #pragma unroll
    for (int i = 0; i < 4; ++i){
      const int p = i*256 + tid;
      const int r = p >> 3, c = p & 7;
      const int gc = c ^ (r & 7);
      __builtin_amdgcn_global_load_lds(
        (const __attribute__((address_space(1))) void*)(A + (size_t)(m0 + r)*K + k0 + gc*8),
        (__attribute__((address_space(3))) void*)(As + p*8), 16, 0, 0);
    }
    #pragma unroll
    for (int i = 0; i < 4; ++i){
      const int p = i*256 + tid;
      const int r = p >> 3, c = p & 7;
      const int gc = c ^ (r & 7);
      __builtin_amdgcn_global_load_lds(
        (const __attribute__((address_space(1))) void*)(Bm + (size_t)(n0 + r)*K + k0 + gc*8),
        (__attribute__((address_space(3))) void*)(Bs + p*8), 16, 0, 0);
    }
    __syncthreads();

    bf16x8 af[2][4], bfr[2][4];
    #pragma unroll
    for (int ks = 0; ks < 2; ++ks){
      #pragma unroll
      for (int m = 0; m < 4; ++m){
        const int R = wm + m*16 + l15;
        const int c = (ks*4 + g) ^ (R & 7);
        af[ks][m] = as_bf(*(const u16x8*)(As + R*64 + c*8));
      }
      #pragma unroll
      for (int n = 0; n < 4; ++n){
        const int R = wn + n*16 + l15;
        const int c = (ks*4 + g) ^ (R & 7);
        bfr[ks][n] = as_bf(*(const u16x8*)(Bs + R*64 + c*8));
      }
    }
    #pragma unroll
    for (int ks = 0; ks < 2; ++ks)
      #pragma unroll
      for (int m = 0; m < 4; ++m)
        #pragma unroll
        for (int n = 0; n < 4; ++n)
          acc[m][n] = __builtin_amdgcn_mfma_f32_16x16x32_bf16(af[ks][m], bfr[ks][n], acc[m][n], 0, 0, 0);
    __syncthreads();
  }

  #pragma unroll
  for (int m = 0; m < 4; ++m)
    #pragma unroll
    for (int n = 0; n < 4; ++n)
      #pragma unroll
      for (int r = 0; r < 4; ++r){
        const int row = m0 + wm + m*16 + g*4 + r;
        const int col = n0 + wn + n*16 + l15;
        o0[(size_t)row*1024 + col] = acc[m][n][r];
      }
}

// Causal flash attention, swapped-QK 32x32, 8 waves x 32 q-rows = 256 q-rows/block.
// R6-proven: 3-buffer ring, counted vmcnt(2), balanced strip pairing.
__global__ __launch_bounds__(512, 4) void attn2(const unsigned short* __restrict__ Q,
                                                const unsigned short* __restrict__ Km,
                                                const unsigned short* __restrict__ Vt,
                                                unsigned short* __restrict__ Y){
  __shared__ __align__(16) unsigned short Ks[3][64*64];
  __shared__ __align__(16) unsigned short Vs[3][64*64];
  const int bh = blockIdx.x, b = bh >> 4, h = bh & 15;
  const int yq = blockIdx.y;
  const int qt = (yq < 4) ? (7 - yq) : (yq - 4);
  const int tid = threadIdx.x;
  const int w = tid >> 6, lane = tid & 63, l31 = lane & 31, hi = lane >> 5;
  const int q0 = qt * 256;
  const int wq0 = q0 + w * 32;
  const int wqmax = wq0 + 31;
  const int nkt = 4 * qt + 4;
  const int qg = wq0 + l31;

  const unsigned short* Ksrc = Km + (size_t)b*TT*CC + h*DD;
  const unsigned short* Vsrc = Vt + (size_t)bh*DD*TT;

  auto stage = [&](int buf, int kt){
    const int r = tid >> 3, c = tid & 7;
    const int gc = c ^ (r & 7);
    __builtin_amdgcn_global_load_lds(
      (const __attribute__((address_space(1))) void*)(Ksrc + (size_t)(kt*64 + r)*CC + gc*8),
      (__attribute__((address_space(3))) void*)(&Ks[buf][tid*8]), 16, 0, 0);
    __builtin_amdgcn_global_load_lds(
      (const __attribute__((address_space(1))) void*)(Vsrc + (size_t)r*TT + (size_t)kt*64 + c*8),
      (__attribute__((address_space(3))) void*)(&Vs[buf][tid*8]), 16, 0, 0);
  };

  stage(0, 0);

  const unsigned short* qrow = Q + ((size_t)b*TT + wq0 + l31)*CC + h*DD;
  bf16x8 qf[4];
  #pragma unroll
  for (int ds = 0; ds < 4; ++ds)
    qf[ds] = as_bf(*(const u16x8*)(qrow + 16*ds + 8*hi));

  int koff[4];
  #pragma unroll
  for (int ds = 0; ds < 4; ++ds)
    koff[ds] = l31*64 + (((2*ds + hi) ^ (l31 & 7)) * 8);

  float m_ = -1e30f, l_ = 0.f;
  f32x16 y0 = {}, y1 = {};

  int cb = 0;
  for (int t = 0; t < nkt; ++t){
    const int nx = (cb == 2) ? 0 : cb + 1;
    if (t + 1 < nkt){
      stage(nx, t + 1);
      asm volatile("s_waitcnt vmcnt(2)" ::: "memory");
    } else {
      asm volatile("s_waitcnt vmcnt(0)" ::: "memory");
    }
    __builtin_amdgcn_s_barrier();

    if (t*64 <= wqmax){
      const unsigned short* Kp = &Ks[cb][0];
      const unsigned short* Vp = &Vs[cb][0];

      f32x16 s0 = {}, s1 = {};
      __builtin_amdgcn_s_setprio(1);
      #pragma unroll
      for (int ds = 0; ds < 4; ++ds){
        bf16x8 kf0 = as_bf(*(const u16x8*)(Kp + koff[ds]));
        s0 = __builtin_amdgcn_mfma_f32_32x32x16_bf16(kf0, qf[ds], s0, 0, 0, 0);
        bf16x8 kf1 = as_bf(*(const u16x8*)(Kp + koff[ds] + 2048));
        s1 = __builtin_amdgcn_mfma_f32_32x32x16_bf16(kf1, qf[ds], s1, 0, 0, 0);
      }
      __builtin_amdgcn_s_setprio(0);

      if (t*64 + 63 > wq0){
        const int kb0 = t*64;
        #pragma unroll
        for (int r = 0; r < 16; ++r){
          const int kr = (r & 3) + 8*(r >> 2) + 4*hi;
          if (kb0 + kr      > qg) s0[r] = -1e30f;
          if (kb0 + 32 + kr > qg) s1[r] = -1e30f;
        }
      }

      float tm[8];
      #pragma unroll
      for (int r = 0; r < 8; ++r) tm[r] = fmaxf(fmaxf(s0[r], s0[r+8]), fmaxf(s1[r], s1[r+8]));
      #pragma unroll
      for (int r = 0; r < 4; ++r) tm[r] = fmaxf(tm[r], tm[r+4]);
      float pmax = fmaxf(fmaxf(tm[0], tm[2]), fmaxf(tm[1], tm[3]));
      pmax = fmaxf(pmax, __shfl_xor(pmax, 32));

      if (!__all(pmax <= m_ + 8.f)){
        const float mnew = fmaxf(m_, pmax);
        const float alpha = ex2(m_ - mnew);
        l_ *= alpha;
        #pragma unroll
        for (int r = 0; r < 16; ++r){
          const float ar = __shfl(alpha, (r & 3) + 8*(r >> 2) + 4*hi);
          y0[r] *= ar; y1[r] *= ar;
        }
        m_ = mnew;
      }

      #pragma unroll
      for (int r = 0; r < 16; ++r) s0[r] = ex2(s0[r] - m_);
      #pragma unroll
      for (int r = 0; r < 16; ++r) s1[r] = ex2(s1[r] - m_);
      float ts[8];
      #pragma unroll
      for (int r = 0; r < 8; ++r) ts[r] = (s0[r] + s0[r+8]) + (s1[r] + s1[r+8]);
      #pragma unroll
      for (int r = 0; r < 4; ++r) ts[r] += ts[r+4];
      float rs = (ts[0] + ts[2]) + (ts[1] + ts[3]);
      rs += __shfl_xor(rs, 32);
      l_ += rs;

      __builtin_amdgcn_s_setprio(1);
      #pragma unroll
      for (int m = 0; m < 4; ++m){
        const f32x16 c = (m < 2) ? s0 : s1;
        const int bx = (m & 1) * 8;
        unsigned A0 = cvt_pk(c[bx+0], c[bx+1]);
        unsigned B0 = cvt_pk(c[bx+4], c[bx+5]);
        pl32swap(A0, B0);
        unsigned A1 = cvt_pk(c[bx+2], c[bx+3]);
        unsigned B1 = cvt_pk(c[bx+6], c[bx+7]);
        pl32swap(A1, B1);
        u32x4 pw; pw.x = A0; pw.y = A1; pw.z = B0; pw.w = B1;
        const bf16x8 pa = __builtin_bit_cast(bf16x8, pw);
        bf16x8 vf0 = as_bf(*(const u16x8*)(Vp + koff[m]));
        y0 = __builtin_amdgcn_mfma_f32_32x32x16_bf16(pa, vf0, y0, 0, 0, 0);
        bf16x8 vf1 = as_bf(*(const u16x8*)(Vp + koff[m] + 2048));
        y1 = __builtin_amdgcn_mfma_f32_32x32x16_bf16(pa, vf1, y1, 0, 0, 0);
      }
      __builtin_amdgcn_s_setprio(0);
    }
    cb = nx;
  }

  const float linv = 1.f / l_;
  #pragma unroll
  for (int r = 0; r < 16; ++r){
    const int qlr = (r & 3) + 8*(r >> 2) + 4*hi;
    const float lr = __shfl(linv, qlr);
    unsigned short* yp = Y + ((size_t)b*TT + wq0 + qlr)*CC + h*DD + l31;
    yp[0]  = f2bf(y0[r] * lr);
    yp[32] = f2bf(y1[r] * lr);
  }
}

extern "C" void kernel_launch(void* const* d_in, const int* in_sizes, int n_in,
                              void* d_out, int out_size, void* d_ws, size_t ws_size,
                              hipStream_t stream){
  const float* x  = (const float*)d_in[0];
  const float* Wk = (const float*)d_in[1];
  const float* Wq = (const float*)d_in[2];
  const float* Wv = (const float*)d_in[3];
  const float* Wp = (const float*)d_in[4];

  const size_t E  = (size_t)BB*TT*CC;
  const size_t Wn = (size_t)CC*CC;
  unsigned short* ws  = (unsigned short*)d_ws;
  unsigned short* xb  = ws;                 // reused as yb after attention
  unsigned short* wkb = xb  + E;            // wkb,wqb,wvb contiguous = B[3072][1024]
  unsigned short* wqb = wkb + Wn;
  unsigned short* wvb = wqb + Wn;
  unsigned short* wpb = wvb + Wn;
  unsigned short* qb  = wpb + Wn;
  unsigned short* kb  = qb  + E;
  unsigned short* vt  = kb  + E;            // V written transposed by QKV GEMM

  (void)wqb; (void)wvb;

  hipFuncSetAttribute(reinterpret_cast<const void*>(gemm256q<12>),
                      hipFuncAttributeMaxDynamicSharedMemorySize, 131072);

  cvt_all<<<12288, 256, 0, stream>>>(x, Wk, Wq, Wv, Wp, xb, wkb);

  // fused QKV at 256^2: B = [Wk; Wq; Wv] -> kb, qb (scaled), vt (transposed+swizzled)
  gemm256q<12><<<dim3(12, 32), 512, 131072, stream>>>(xb, wkb, kb, qb, vt);

  unsigned short* yb = xb;
  attn2<<<dim3(BB*HH, TT/256), 512, 0, stream>>>(qb, kb, vt, yb);

  gemm128<8><<<dim3(8, 64), 256, 0, stream>>>(yb, wpb, (float*)d_out);
}

// Round 17
// 152.529 us; speedup vs baseline: 1.0813x; 1.0001x over previous
//
#include <hip/hip_runtime.h>

typedef __bf16 bf16x8 __attribute__((ext_vector_type(8)));
typedef float f32x4 __attribute__((ext_vector_type(4)));
typedef float f32x16 __attribute__((ext_vector_type(16)));
typedef unsigned short u16x8 __attribute__((ext_vector_type(8)));
typedef unsigned short u16x4 __attribute__((ext_vector_type(4)));
typedef unsigned u32x4 __attribute__((ext_vector_type(4)));

#define BB 4
#define TT 2048
#define CC 1024
#define HH 16
#define DD 64

__device__ __forceinline__ unsigned short f2bf(float f){
  unsigned u = __builtin_bit_cast(unsigned, f);
  u += 0x7FFFu + ((u >> 16) & 1u);
  return (unsigned short)(u >> 16);
}
__device__ __forceinline__ bf16x8 as_bf(u16x8 v){ return __builtin_bit_cast(bf16x8, v); }
__device__ __forceinline__ unsigned cvt_pk(float lo, float hi){
  unsigned r; asm("v_cvt_pk_bf16_f32 %0, %1, %2" : "=v"(r) : "v"(lo), "v"(hi)); return r;
}
__device__ __forceinline__ void pl32swap(unsigned &a, unsigned &b){
  asm("v_permlane32_swap_b32 %0, %1" : "+v"(a), "+v"(b));
}
__device__ __forceinline__ float ex2(float x){
#if __has_builtin(__builtin_amdgcn_exp2f)
  return __builtin_amdgcn_exp2f(x);
#else
  return __expf(x * 0.6931471805599453f);
#endif
}

// all 5 fp32->bf16 conversions in one launch
__global__ __launch_bounds__(256) void cvt_all(const float* __restrict__ x,
                                               const float* __restrict__ Wk,
                                               const float* __restrict__ Wq,
                                               const float* __restrict__ Wv,
                                               const float* __restrict__ Wp,
                                               unsigned short* __restrict__ xb,
                                               unsigned short* __restrict__ wb){
  const int i = blockIdx.x * 256 + threadIdx.x;           // one float4 per thread
  constexpr int EX = (BB*TT*CC)/4;                        // 2,097,152
  const float* src; unsigned short* dst; int off;
  if (i < EX){ src = x; dst = xb; off = i; }
  else {
    const int j = i - EX;
    const int wsel = j >> 18;                             // Wn/4 = 2^18
    off = j & 262143;
    src = (wsel==0) ? Wk : (wsel==1) ? Wq : (wsel==2) ? Wv : Wp;
    dst = wb + ((size_t)wsel << 20);                      // Wn = 2^20
  }
  const float4 f = ((const float4*)src)[off];
  u16x4 o; o.x = f2bf(f.x); o.y = f2bf(f.y); o.z = f2bf(f.z); o.w = f2bf(f.w);
  ((u16x4*)dst)[off] = o;
}

// ---------------- 256x256 QKV GEMM, read-ahead pipeline, 5-slot ring depth-4 ----------------
// C = A @ B^T, A: 8192x1024 bf16, B: 3072x1024 bf16 ([Wk;Wq;Wv]).
// 8 waves (2Mx4N), per-wave 128x64. LDS: 5 half-tile slots x (A 256x32 + B 256x32)
// = 160 KB. Phase p: stage(slot (p+4)%5 = (p-1)%5, half p+4) -> vmcnt(12) -> lgkm(0)
// -> barrier -> MFMA(p) [frags pre-read] -> ds_read(half p+1, slot (p+1)%5).
// WAR invariant (R12-proven): stage targets the slot read two phases ago, whose readers
// were lgkm0'd before barrier p-1 (cross-wave certified). Ledger: entering p in-flight
// {p+1,p+2,p+3}=12; +4 -> vmcnt(12) proves half p+1 landed. Tail drains 8/4/0.
// tsel 0 -> K (o0), 1 -> Q (o1, *log2e/8), 2 -> V^T (o2=Vt).
template<int NX>
__global__ __launch_bounds__(512, 2) void gemm256q(const unsigned short* __restrict__ A,
                                                   const unsigned short* __restrict__ Bm,
                                                   void* __restrict__ o0, void* __restrict__ o1,
                                                   void* __restrict__ o2){
  constexpr int K = 1024;
  constexpr int NWG = NX * 32;
  extern __shared__ unsigned short lds[];                 // 5 x 16384 elems (160 KB)
  const int tid = threadIdx.x;
  const int flat = blockIdx.y * NX + blockIdx.x;
  const int swz = (flat & 7) * (NWG / 8) + (flat >> 3);   // bijective (NWG%8==0)
  const int n0 = (swz % NX) * 256;
  const int m0 = (swz / NX) * 256;
  const int w = tid >> 6, lane = tid & 63, l15 = lane & 15, g = lane >> 4;
  const int wm = (w >> 2) * 128;                          // {0,128}
  const int wn = (w & 3) * 64;                            // {0,64,128,192}
  const int tsel = n0 >> 10;                              // block-uniform

  // staging lane constants (proven 32-k swizzle)
  const int sc_q = lane >> 2;
  const int sc_g = (lane & 3) ^ ((lane >> 3) & 3);
  const int rd_cc = g ^ ((l15 >> 1) & 3);

  // stage half h (= tile h>>1, k-half h&1) into slot s: 4 loads/thread (2 A + 2 B)
  auto stage = [&](int s, int h){
    const int kt = h >> 1, ks = h & 1;
    #pragma unroll
    for (int j = 0; j < 2; ++j){
      const int wl = j*8 + w;
      const int r = wl*16 + sc_q;
      __builtin_amdgcn_global_load_lds(
        (const __attribute__((address_space(1))) void*)(A + (size_t)(m0 + r)*K + kt*64 + ks*32 + sc_g*8),
        (__attribute__((address_space(3))) void*)(lds + s*16384 + wl*512 + lane*8), 16, 0, 0);
      __builtin_amdgcn_global_load_lds(
        (const __attribute__((address_space(1))) void*)(Bm + (size_t)(n0 + r)*K + kt*64 + ks*32 + sc_g*8),
        (__attribute__((address_space(3))) void*)(lds + s*16384 + 8192 + wl*512 + lane*8), 16, 0, 0);
    }
  };

  int aoff[8], boff[4];
  #pragma unroll
  for (int m = 0; m < 8; ++m) aoff[m] = (wm + m*16 + l15)*32 + rd_cc*8;
  #pragma unroll
  for (int n = 0; n < 4; ++n) boff[n] = 8192 + (wn + n*16 + l15)*32 + rd_cc*8;

  auto dsread = [&](int sbase, bf16x8* af, bf16x8* bfr){
    const unsigned short* base = lds + sbase;
    #pragma unroll
    for (int n = 0; n < 4; ++n) bfr[n] = as_bf(*(const u16x8*)(base + boff[n]));
    #pragma unroll
    for (int m = 0; m < 8; ++m) af[m] = as_bf(*(const u16x8*)(base + aoff[m]));
  };

  f32x4 acc[8][4] = {};
  auto mfma32 = [&](bf16x8* af, bf16x8* bfr){
    __builtin_amdgcn_s_setprio(1);
    #pragma unroll
    for (int m = 0; m < 8; ++m)
      #pragma unroll
      for (int n = 0; n < 4; ++n)
        acc[m][n] = __builtin_amdgcn_mfma_f32_16x16x32_bf16(af[m], bfr[n], acc[m][n], 0, 0, 0);
    __builtin_amdgcn_s_setprio(0);
  };

  bf16x8 afA[8], bfA[4], afB[8], bfB[4];

  // prologue: halves 0..3 -> slots 0..3 (16 loads); half0 landed -> pre-read set A
  stage(0,0); stage(1,1); stage(2,2); stage(3,3);
  asm volatile("s_waitcnt vmcnt(12)" ::: "memory");
  __builtin_amdgcn_s_barrier();
  dsread(0, afA, bfA);

  // PHA: even phase (use set A, read into set B); PHB: odd phase (swap).
#define PHC(SSLOT, HALF, VMC, RSLOT, AF_U, BF_U, AF_R, BF_R)       \
  do {                                                             \
    if (SSLOT >= 0) stage(SSLOT, HALF);                            \
    asm volatile("s_waitcnt vmcnt(" #VMC ")" ::: "memory");        \
    asm volatile("s_waitcnt lgkmcnt(0)" ::: "memory");             \
    __builtin_amdgcn_s_barrier();                                  \
    __builtin_amdgcn_sched_barrier(0);                             \
    mfma32(AF_U, BF_U);                                            \
    dsread((RSLOT)*16384, AF_R, BF_R);                             \
  } while (0)
#define PHA(SSLOT, HALF, VMC, RSLOT) PHC(SSLOT, HALF, VMC, RSLOT, afA, bfA, afB, bfB)
#define PHB(SSLOT, HALF, VMC, RSLOT) PHC(SSLOT, HALF, VMC, RSLOT, afB, bfB, afA, bfA)

  PHA(4, 4,12,1);  PHB(0, 5,12,2);  PHA(1, 6,12,3);  PHB(2, 7,12,4);
  PHA(3, 8,12,0);  PHB(4, 9,12,1);  PHA(0,10,12,2);  PHB(1,11,12,3);
  PHA(2,12,12,4);  PHB(3,13,12,0);  PHA(4,14,12,1);  PHB(0,15,12,2);
  PHA(1,16,12,3);  PHB(2,17,12,4);  PHA(3,18,12,0);  PHB(4,19,12,1);
  PHA(0,20,12,2);  PHB(1,21,12,3);  PHA(2,22,12,4);  PHB(3,23,12,0);
  PHA(4,24,12,1);  PHB(0,25,12,2);  PHA(1,26,12,3);  PHB(2,27,12,4);
  PHA(3,28,12,0);  PHB(4,29,12,1);  PHA(0,30,12,2);  PHB(1,31,12,3);
  PHA(-1,0, 8,4);  PHB(-1,0, 4,0);  PHA(-1,0, 0,1);
  asm volatile("s_waitcnt lgkmcnt(0)" ::: "memory");
  __builtin_amdgcn_sched_barrier(0);
  mfma32(afB, bfB);                                // p31 (half31, slot1)
#undef PHA
#undef PHB
#undef PHC

  if (tsel == 2){
    // V epilogue: write transposed to Vt [B*H][D][T] with XOR k-chunk swizzle (u16x4 runs).
    const int bq = m0 >> 11;
    const int t0 = m0 & 2047;
    unsigned short* vt = (unsigned short*)o2;
    #pragma unroll
    for (int n = 0; n < 4; ++n){
      const int cg = (n0 & 1023) + wn + n*16 + l15;        // channel 0..1023
      const int h = cg >> 6, d = cg & 63;
      unsigned short* base = vt + ((size_t)(bq*HH + h)*DD + d)*TT;
      #pragma unroll
      for (int m = 0; m < 8; ++m){
        const int t = t0 + wm + m*16 + g*4;
        const int kt = t >> 6;
        const int cch = ((t >> 3) & 7) ^ (d & 7);
        u16x4 pv;
        pv.x = f2bf(acc[m][n][0]); pv.y = f2bf(acc[m][n][1]);
        pv.z = f2bf(acc[m][n][2]); pv.w = f2bf(acc[m][n][3]);
        *(u16x4*)(base + (size_t)kt*64 + cch*8 + (t & 7)) = pv;
      }
    }
    return;
  }

  const float sc = (tsel == 1) ? 0.18033688011112042f : 1.0f;  // log2(e)/8
  unsigned short* outb = (unsigned short*)(tsel == 0 ? o0 : o1);
  #pragma unroll
  for (int m = 0; m < 8; ++m)
    #pragma unroll
    for (int n = 0; n < 4; ++n)
      #pragma unroll
      for (int r = 0; r < 4; ++r){
        const int row = m0 + wm + m*16 + g*4 + r;
        const int col = (n0 & 1023) + wn + n*16 + l15;
        outb[(size_t)row*1024 + col] = f2bf(acc[m][n][r] * sc);
      }
}

// ---------------- proven 128^2 GEMM (used for output projection) ----------------
template<int NX>
__global__ __launch_bounds__(256) void gemm128(const unsigned short* __restrict__ A,
                                               const unsigned short* __restrict__ Bm,
                                               float* __restrict__ o0){
  constexpr int K = 1024;
  constexpr int NWG = NX * 64;
  __shared__ __align__(16) unsigned short As[128*64];
  __shared__ __align__(16) unsigned short Bs[128*64];
  const int tid = threadIdx.x;
  const int flat = blockIdx.y * NX + blockIdx.x;
  const int swz = (flat & 7) * (NWG / 8) + (flat >> 3);
  const int n0 = (swz % NX) * 128;
  const int m0 = (swz / NX) * 128;
  const int w = tid >> 6, lane = tid & 63, l15 = lane & 15, g = lane >> 4;
  const int wm = (w >> 1) * 64, wn = (w & 1) * 64;

  f32x4 acc[4][4] = {};

  for (int k0 = 0; k0 < K; k0 += 64){
    #pragma unroll
    for (int i = 0; i < 4; ++i){
      const int p = i*256 + tid;
      const int r = p >> 3, c = p & 7;
      const int gc = c ^ (r & 7);
      __builtin_amdgcn_global_load_lds(
        (const __attribute__((address_space(1))) void*)(A + (size_t)(m0 + r)*K + k0 + gc*8),
        (__attribute__((address_space(3))) void*)(As + p*8), 16, 0, 0);
    }
    #pragma unroll
    for (int i = 0; i < 4; ++i){
      const int p = i*256 + tid;
      const int r = p >> 3, c = p & 7;
      const int gc = c ^ (r & 7);
      __builtin_amdgcn_global_load_lds(
        (const __attribute__((address_space(1))) void*)(Bm + (size_t)(n0 + r)*K + k0 + gc*8),
        (__attribute__((address_space(3))) void*)(Bs + p*8), 16, 0, 0);
    }
    __syncthreads();

    bf16x8 af[2][4], bfr[2][4];
    #pragma unroll
    for (int ks = 0; ks < 2; ++ks){
      #pragma unroll
      for (int m = 0; m < 4; ++m){
        const int R = wm + m*16 + l15;
        const int c = (ks*4 + g) ^ (R & 7);
        af[ks][m] = as_bf(*(const u16x8*)(As + R*64 + c*8));
      }
      #pragma unroll
      for (int n = 0; n < 4; ++n){
        const int R = wn + n*16 + l15;
        const int c = (ks*4 + g) ^ (R & 7);
        bfr[ks][n] = as_bf(*(const u16x8*)(Bs + R*64 + c*8));
      }
    }
    #pragma unroll
    for (int ks = 0; ks < 2; ++ks)
      #pragma unroll
      for (int m = 0; m < 4; ++m)
        #pragma unroll
        for (int n = 0; n < 4; ++n)
          acc[m][n] = __builtin_amdgcn_mfma_f32_16x16x32_bf16(af[ks][m], bfr[ks][n], acc[m][n], 0, 0, 0);
    __syncthreads();
  }

  #pragma unroll
  for (int m = 0; m < 4; ++m)
    #pragma unroll
    for (int n = 0; n < 4; ++n)
      #pragma unroll
      for (int r = 0; r < 4; ++r){
        const int row = m0 + wm + m*16 + g*4 + r;
        const int col = n0 + wn + n*16 + l15;
        o0[(size_t)row*1024 + col] = acc[m][n][r];
      }
}

// Causal flash attention, swapped-QK 32x32, 8 waves x 32 q-rows = 256 q-rows/block.
// R6-proven: 3-buffer ring, counted vmcnt(2), balanced strip pairing.
__global__ __launch_bounds__(512, 4) void attn2(const unsigned short* __restrict__ Q,
                                                const unsigned short* __restrict__ Km,
                                                const unsigned short* __restrict__ Vt,
                                                unsigned short* __restrict__ Y){
  __shared__ __align__(16) unsigned short Ks[3][64*64];
  __shared__ __align__(16) unsigned short Vs[3][64*64];
  const int bh = blockIdx.x, b = bh >> 4, h = bh & 15;
  const int yq = blockIdx.y;
  const int qt = (yq < 4) ? (7 - yq) : (yq - 4);
  const int tid = threadIdx.x;
  const int w = tid >> 6, lane = tid & 63, l31 = lane & 31, hi = lane >> 5;
  const int q0 = qt * 256;
  const int wq0 = q0 + w * 32;
  const int wqmax = wq0 + 31;
  const int nkt = 4 * qt + 4;
  const int qg = wq0 + l31;

  const unsigned short* Ksrc = Km + (size_t)b*TT*CC + h*DD;
  const unsigned short* Vsrc = Vt + (size_t)bh*DD*TT;

  auto stage = [&](int buf, int kt){
    const int r = tid >> 3, c = tid & 7;
    const int gc = c ^ (r & 7);
    __builtin_amdgcn_global_load_lds(
      (const __attribute__((address_space(1))) void*)(Ksrc + (size_t)(kt*64 + r)*CC + gc*8),
      (__attribute__((address_space(3))) void*)(&Ks[buf][tid*8]), 16, 0, 0);
    __builtin_amdgcn_global_load_lds(
      (const __attribute__((address_space(1))) void*)(Vsrc + (size_t)r*TT + (size_t)kt*64 + c*8),
      (__attribute__((address_space(3))) void*)(&Vs[buf][tid*8]), 16, 0, 0);
  };

  stage(0, 0);

  const unsigned short* qrow = Q + ((size_t)b*TT + wq0 + l31)*CC + h*DD;
  bf16x8 qf[4];
  #pragma unroll
  for (int ds = 0; ds < 4; ++ds)
    qf[ds] = as_bf(*(const u16x8*)(qrow + 16*ds + 8*hi));

  int koff[4];
  #pragma unroll
  for (int ds = 0; ds < 4; ++ds)
    koff[ds] = l31*64 + (((2*ds + hi) ^ (l31 & 7)) * 8);

  float m_ = -1e30f, l_ = 0.f;
  f32x16 y0 = {}, y1 = {};

  int cb = 0;
  for (int t = 0; t < nkt; ++t){
    const int nx = (cb == 2) ? 0 : cb + 1;
    if (t + 1 < nkt){
      stage(nx, t + 1);
      asm volatile("s_waitcnt vmcnt(2)" ::: "memory");
    } else {
      asm volatile("s_waitcnt vmcnt(0)" ::: "memory");
    }
    __builtin_amdgcn_s_barrier();

    if (t*64 <= wqmax){
      const unsigned short* Kp = &Ks[cb][0];
      const unsigned short* Vp = &Vs[cb][0];

      f32x16 s0 = {}, s1 = {};
      __builtin_amdgcn_s_setprio(1);
      #pragma unroll
      for (int ds = 0; ds < 4; ++ds){
        bf16x8 kf0 = as_bf(*(const u16x8*)(Kp + koff[ds]));
        s0 = __builtin_amdgcn_mfma_f32_32x32x16_bf16(kf0, qf[ds], s0, 0, 0, 0);
        bf16x8 kf1 = as_bf(*(const u16x8*)(Kp + koff[ds] + 2048));
        s1 = __builtin_amdgcn_mfma_f32_32x32x16_bf16(kf1, qf[ds], s1, 0, 0, 0);
      }
      __builtin_amdgcn_s_setprio(0);

      if (t*64 + 63 > wq0){
        const int kb0 = t*64;
        #pragma unroll
        for (int r = 0; r < 16; ++r){
          const int kr = (r & 3) + 8*(r >> 2) + 4*hi;
          if (kb0 + kr      > qg) s0[r] = -1e30f;
          if (kb0 + 32 + kr > qg) s1[r] = -1e30f;
        }
      }

      float tm[8];
      #pragma unroll
      for (int r = 0; r < 8; ++r) tm[r] = fmaxf(fmaxf(s0[r], s0[r+8]), fmaxf(s1[r], s1[r+8]));
      #pragma unroll
      for (int r = 0; r < 4; ++r) tm[r] = fmaxf(tm[r], tm[r+4]);
      float pmax = fmaxf(fmaxf(tm[0], tm[2]), fmaxf(tm[1], tm[3]));
      pmax = fmaxf(pmax, __shfl_xor(pmax, 32));

      if (!__all(pmax <= m_ + 8.f)){
        const float mnew = fmaxf(m_, pmax);
        const float alpha = ex2(m_ - mnew);
        l_ *= alpha;
        #pragma unroll
        for (int r = 0; r < 16; ++r){
          const float ar = __shfl(alpha, (r & 3) + 8*(r >> 2) + 4*hi);
          y0[r] *= ar; y1[r] *= ar;
        }
        m_ = mnew;
      }

      #pragma unroll
      for (int r = 0; r < 16; ++r) s0[r] = ex2(s0[r] - m_);
      #pragma unroll
      for (int r = 0; r < 16; ++r) s1[r] = ex2(s1[r] - m_);
      float ts[8];
      #pragma unroll
      for (int r = 0; r < 8; ++r) ts[r] = (s0[r] + s0[r+8]) + (s1[r] + s1[r+8]);
      #pragma unroll
      for (int r = 0; r < 4; ++r) ts[r] += ts[r+4];
      float rs = (ts[0] + ts[2]) + (ts[1] + ts[3]);
      rs += __shfl_xor(rs, 32);
      l_ += rs;

      __builtin_amdgcn_s_setprio(1);
      #pragma unroll
      for (int m = 0; m < 4; ++m){
        const f32x16 c = (m < 2) ? s0 : s1;
        const int bx = (m & 1) * 8;
        unsigned A0 = cvt_pk(c[bx+0], c[bx+1]);
        unsigned B0 = cvt_pk(c[bx+4], c[bx+5]);
        pl32swap(A0, B0);
        unsigned A1 = cvt_pk(c[bx+2], c[bx+3]);
        unsigned B1 = cvt_pk(c[bx+6], c[bx+7]);
        pl32swap(A1, B1);
        u32x4 pw; pw.x = A0; pw.y = A1; pw.z = B0; pw.w = B1;
        const bf16x8 pa = __builtin_bit_cast(bf16x8, pw);
        bf16x8 vf0 = as_bf(*(const u16x8*)(Vp + koff[m]));
        y0 = __builtin_amdgcn_mfma_f32_32x32x16_bf16(pa, vf0, y0, 0, 0, 0);
        bf16x8 vf1 = as_bf(*(const u16x8*)(Vp + koff[m] + 2048));
        y1 = __builtin_amdgcn_mfma_f32_32x32x16_bf16(pa, vf1, y1, 0, 0, 0);
      }
      __builtin_amdgcn_s_setprio(0);
    }
    cb = nx;
  }

  const float linv = 1.f / l_;
  #pragma unroll
  for (int r = 0; r < 16; ++r){
    const int qlr = (r & 3) + 8*(r >> 2) + 4*hi;
    const float lr = __shfl(linv, qlr);
    unsigned short* yp = Y + ((size_t)b*TT + wq0 + qlr)*CC + h*DD + l31;
    yp[0]  = f2bf(y0[r] * lr);
    yp[32] = f2bf(y1[r] * lr);
  }
}

extern "C" void kernel_launch(void* const* d_in, const int* in_sizes, int n_in,
                              void* d_out, int out_size, void* d_ws, size_t ws_size,
                              hipStream_t stream){
  const float* x  = (const float*)d_in[0];
  const float* Wk = (const float*)d_in[1];
  const float* Wq = (const float*)d_in[2];
  const float* Wv = (const float*)d_in[3];
  const float* Wp = (const float*)d_in[4];

  const size_t E  = (size_t)BB*TT*CC;
  const size_t Wn = (size_t)CC*CC;
  unsigned short* ws  = (unsigned short*)d_ws;
  unsigned short* xb  = ws;                 // reused as yb after attention
  unsigned short* wkb = xb  + E;            // wkb,wqb,wvb contiguous = B[3072][1024]
  unsigned short* wqb = wkb + Wn;
  unsigned short* wvb = wqb + Wn;
  unsigned short* wpb = wvb + Wn;
  unsigned short* qb  = wpb + Wn;
  unsigned short* kb  = qb  + E;
  unsigned short* vt  = kb  + E;            // V written transposed by QKV GEMM

  (void)wqb; (void)wvb;

  hipFuncSetAttribute(reinterpret_cast<const void*>(gemm256q<12>),
                      hipFuncAttributeMaxDynamicSharedMemorySize, 163840);

  cvt_all<<<12288, 256, 0, stream>>>(x, Wk, Wq, Wv, Wp, xb, wkb);

  // fused QKV at 256^2: B = [Wk; Wq; Wv] -> kb, qb (scaled), vt (transposed+swizzled)
  gemm256q<12><<<dim3(12, 32), 512, 163840, stream>>>(xb, wkb, kb, qb, vt);

  unsigned short* yb = xb;
  attn2<<<dim3(BB*HH, TT/256), 512, 0, stream>>>(qb, kb, vt, yb);

  gemm128<8><<<dim3(8, 64), 256, 0, stream>>>(yb, wpb, (float*)d_out);
}

// Round 18
// 152.407 us; speedup vs baseline: 1.0822x; 1.0008x over previous
//
#include <hip/hip_runtime.h>

typedef __bf16 bf16x8 __attribute__((ext_vector_type(8)));
typedef float f32x4 __attribute__((ext_vector_type(4)));
typedef float f32x16 __attribute__((ext_vector_type(16)));
typedef unsigned short u16x8 __attribute__((ext_vector_type(8)));
typedef unsigned short u16x4 __attribute__((ext_vector_type(4)));
typedef unsigned u32x4 __attribute__((ext_vector_type(4)));

#define BB 4
#define TT 2048
#define CC 1024
#define HH 16
#define DD 64

__device__ __forceinline__ unsigned short f2bf(float f){
  unsigned u = __builtin_bit_cast(unsigned, f);
  u += 0x7FFFu + ((u >> 16) & 1u);
  return (unsigned short)(u >> 16);
}
__device__ __forceinline__ bf16x8 as_bf(u16x8 v){ return __builtin_bit_cast(bf16x8, v); }
__device__ __forceinline__ unsigned cvt_pk(float lo, float hi){
  unsigned r; asm("v_cvt_pk_bf16_f32 %0, %1, %2" : "=v"(r) : "v"(lo), "v"(hi)); return r;
}
__device__ __forceinline__ void pl32swap(unsigned &a, unsigned &b){
  asm("v_permlane32_swap_b32 %0, %1" : "+v"(a), "+v"(b));
}
__device__ __forceinline__ float ex2(float x){
#if __has_builtin(__builtin_amdgcn_exp2f)
  return __builtin_amdgcn_exp2f(x);
#else
  return __expf(x * 0.6931471805599453f);
#endif
}

// all 5 fp32->bf16 conversions in one launch
__global__ __launch_bounds__(256) void cvt_all(const float* __restrict__ x,
                                               const float* __restrict__ Wk,
                                               const float* __restrict__ Wq,
                                               const float* __restrict__ Wv,
                                               const float* __restrict__ Wp,
                                               unsigned short* __restrict__ xb,
                                               unsigned short* __restrict__ wb){
  const int i = blockIdx.x * 256 + threadIdx.x;           // one float4 per thread
  constexpr int EX = (BB*TT*CC)/4;                        // 2,097,152
  const float* src; unsigned short* dst; int off;
  if (i < EX){ src = x; dst = xb; off = i; }
  else {
    const int j = i - EX;
    const int wsel = j >> 18;                             // Wn/4 = 2^18
    off = j & 262143;
    src = (wsel==0) ? Wk : (wsel==1) ? Wq : (wsel==2) ? Wv : Wp;
    dst = wb + ((size_t)wsel << 20);                      // Wn = 2^20
  }
  const float4 f = ((const float4*)src)[off];
  u16x4 o; o.x = f2bf(f.x); o.y = f2bf(f.y); o.z = f2bf(f.z); o.w = f2bf(f.w);
  ((u16x4*)dst)[off] = o;
}

// ------- 256x256 QKV GEMM, read-ahead pipeline, 5-slot ring, INTERLEAVED phase body -------
// C = A @ B^T, A: 8192x1024 bf16, B: 3072x1024 bf16 ([Wk;Wq;Wv]).
// 8 waves (2Mx4N), per-wave 128x64. LDS: 5 half-tile slots x (A 256x32 + B 256x32) = 160 KB.
// Phase p: stage(slot (p-1)%5, half p+4) -> vmcnt(12) -> lgkm(0) -> barrier -> sched_barrier
// -> {4 B-reads(p+1); per m: 1 A-read(p+1) + 4 MFMA(p)} interleaved (feeds LDS + matrix
// pipes simultaneously; no setprio bracket to clump the MFMA burst).
// WAR invariant (R12/R16-proven): stage targets the slot read two phases ago. Ledger:
// entering p in-flight {p+1,p+2,p+3}=12; +4 -> vmcnt(12) proves half p+1 landed.
// tsel 0 -> K (o0), 1 -> Q (o1, *log2e/8), 2 -> V^T (o2=Vt).
template<int NX>
__global__ __launch_bounds__(512, 2) void gemm256q(const unsigned short* __restrict__ A,
                                                   const unsigned short* __restrict__ Bm,
                                                   void* __restrict__ o0, void* __restrict__ o1,
                                                   void* __restrict__ o2){
  constexpr int K = 1024;
  constexpr int NWG = NX * 32;
  extern __shared__ unsigned short lds[];                 // 5 x 16384 elems (160 KB)
  const int tid = threadIdx.x;
  const int flat = blockIdx.y * NX + blockIdx.x;
  const int swz = (flat & 7) * (NWG / 8) + (flat >> 3);   // bijective (NWG%8==0)
  const int n0 = (swz % NX) * 256;
  const int m0 = (swz / NX) * 256;
  const int w = tid >> 6, lane = tid & 63, l15 = lane & 15, g = lane >> 4;
  const int wm = (w >> 2) * 128;                          // {0,128}
  const int wn = (w & 3) * 64;                            // {0,64,128,192}
  const int tsel = n0 >> 10;                              // block-uniform

  // staging lane constants (proven 32-k swizzle)
  const int sc_q = lane >> 2;
  const int sc_g = (lane & 3) ^ ((lane >> 3) & 3);
  const int rd_cc = g ^ ((l15 >> 1) & 3);

  // stage half h (= tile h>>1, k-half h&1) into slot s: 4 loads/thread (2 A + 2 B)
  auto stage = [&](int s, int h){
    const int kt = h >> 1, ks = h & 1;
    #pragma unroll
    for (int j = 0; j < 2; ++j){
      const int wl = j*8 + w;
      const int r = wl*16 + sc_q;
      __builtin_amdgcn_global_load_lds(
        (const __attribute__((address_space(1))) void*)(A + (size_t)(m0 + r)*K + kt*64 + ks*32 + sc_g*8),
        (__attribute__((address_space(3))) void*)(lds + s*16384 + wl*512 + lane*8), 16, 0, 0);
      __builtin_amdgcn_global_load_lds(
        (const __attribute__((address_space(1))) void*)(Bm + (size_t)(n0 + r)*K + kt*64 + ks*32 + sc_g*8),
        (__attribute__((address_space(3))) void*)(lds + s*16384 + 8192 + wl*512 + lane*8), 16, 0, 0);
    }
  };

  int aoff[8], boff[4];
  #pragma unroll
  for (int m = 0; m < 8; ++m) aoff[m] = (wm + m*16 + l15)*32 + rd_cc*8;
  #pragma unroll
  for (int n = 0; n < 4; ++n) boff[n] = 8192 + (wn + n*16 + l15)*32 + rd_cc*8;

  auto dsread = [&](int sbase, bf16x8* af, bf16x8* bfr){
    const unsigned short* base = lds + sbase;
    #pragma unroll
    for (int n = 0; n < 4; ++n) bfr[n] = as_bf(*(const u16x8*)(base + boff[n]));
    #pragma unroll
    for (int m = 0; m < 8; ++m) af[m] = as_bf(*(const u16x8*)(base + aoff[m]));
  };

  f32x4 acc[8][4] = {};

  bf16x8 afA[8], bfA[4], afB[8], bfB[4];

  // prologue: halves 0..3 -> slots 0..3 (16 loads); half0 landed -> pre-read set A
  stage(0,0); stage(1,1); stage(2,2); stage(3,3);
  asm volatile("s_waitcnt vmcnt(12)" ::: "memory");
  __builtin_amdgcn_s_barrier();
  dsread(0, afA, bfA);

  // PHA: even phase (use set A, read into set B); PHB: odd phase (swap).
  // Phase body interleaves ds_read(p+1) with MFMA(p): both pipes fed concurrently.
#define PHC(SSLOT, HALF, VMC, RSLOT, AF_U, BF_U, AF_R, BF_R)                         \
  do {                                                                               \
    if (SSLOT >= 0) stage(SSLOT, HALF);                                              \
    asm volatile("s_waitcnt vmcnt(" #VMC ")" ::: "memory");                          \
    asm volatile("s_waitcnt lgkmcnt(0)" ::: "memory");                               \
    __builtin_amdgcn_s_barrier();                                                    \
    __builtin_amdgcn_sched_barrier(0);                                               \
    {                                                                                \
      const unsigned short* base_ = lds + (RSLOT)*16384;                             \
      _Pragma("unroll")                                                              \
      for (int n_ = 0; n_ < 4; ++n_) BF_R[n_] = as_bf(*(const u16x8*)(base_ + boff[n_])); \
      _Pragma("unroll")                                                              \
      for (int m_ = 0; m_ < 8; ++m_){                                                \
        AF_R[m_] = as_bf(*(const u16x8*)(base_ + aoff[m_]));                         \
        _Pragma("unroll")                                                            \
        for (int n_ = 0; n_ < 4; ++n_)                                               \
          acc[m_][n_] = __builtin_amdgcn_mfma_f32_16x16x32_bf16(AF_U[m_], BF_U[n_], acc[m_][n_], 0, 0, 0); \
      }                                                                              \
    }                                                                                \
  } while (0)
#define PHA(SSLOT, HALF, VMC, RSLOT) PHC(SSLOT, HALF, VMC, RSLOT, afA, bfA, afB, bfB)
#define PHB(SSLOT, HALF, VMC, RSLOT) PHC(SSLOT, HALF, VMC, RSLOT, afB, bfB, afA, bfA)

  PHA(4, 4,12,1);  PHB(0, 5,12,2);  PHA(1, 6,12,3);  PHB(2, 7,12,4);
  PHA(3, 8,12,0);  PHB(4, 9,12,1);  PHA(0,10,12,2);  PHB(1,11,12,3);
  PHA(2,12,12,4);  PHB(3,13,12,0);  PHA(4,14,12,1);  PHB(0,15,12,2);
  PHA(1,16,12,3);  PHB(2,17,12,4);  PHA(3,18,12,0);  PHB(4,19,12,1);
  PHA(0,20,12,2);  PHB(1,21,12,3);  PHA(2,22,12,4);  PHB(3,23,12,0);
  PHA(4,24,12,1);  PHB(0,25,12,2);  PHA(1,26,12,3);  PHB(2,27,12,4);
  PHA(3,28,12,0);  PHB(4,29,12,1);  PHA(0,30,12,2);  PHB(1,31,12,3);
  PHA(-1,0, 8,4);  PHB(-1,0, 4,0);  PHA(-1,0, 0,1);
  asm volatile("s_waitcnt lgkmcnt(0)" ::: "memory");
  __builtin_amdgcn_sched_barrier(0);
  #pragma unroll
  for (int m = 0; m < 8; ++m)
    #pragma unroll
    for (int n = 0; n < 4; ++n)
      acc[m][n] = __builtin_amdgcn_mfma_f32_16x16x32_bf16(afB[m], bfB[n], acc[m][n], 0, 0, 0);
#undef PHA
#undef PHB
#undef PHC

  if (tsel == 2){
    // V epilogue: write transposed to Vt [B*H][D][T] with XOR k-chunk swizzle (u16x4 runs).
    const int bq = m0 >> 11;
    const int t0 = m0 & 2047;
    unsigned short* vt = (unsigned short*)o2;
    #pragma unroll
    for (int n = 0; n < 4; ++n){
      const int cg = (n0 & 1023) + wn + n*16 + l15;        // channel 0..1023
      const int h = cg >> 6, d = cg & 63;
      unsigned short* base = vt + ((size_t)(bq*HH + h)*DD + d)*TT;
      #pragma unroll
      for (int m = 0; m < 8; ++m){
        const int t = t0 + wm + m*16 + g*4;
        const int kt = t >> 6;
        const int cch = ((t >> 3) & 7) ^ (d & 7);
        u16x4 pv;
        pv.x = f2bf(acc[m][n][0]); pv.y = f2bf(acc[m][n][1]);
        pv.z = f2bf(acc[m][n][2]); pv.w = f2bf(acc[m][n][3]);
        *(u16x4*)(base + (size_t)kt*64 + cch*8 + (t & 7)) = pv;
      }
    }
    return;
  }

  const float sc = (tsel == 1) ? 0.18033688011112042f : 1.0f;  // log2(e)/8
  unsigned short* outb = (unsigned short*)(tsel == 0 ? o0 : o1);
  #pragma unroll
  for (int m = 0; m < 8; ++m)
    #pragma unroll
    for (int n = 0; n < 4; ++n)
      #pragma unroll
      for (int r = 0; r < 4; ++r){
        const int row = m0 + wm + m*16 + g*4 + r;
        const int col = (n0 & 1023) + wn + n*16 + l15;
        outb[(size_t)row*1024 + col] = f2bf(acc[m][n][r] * sc);
      }
}

// ---------------- proven 128^2 GEMM (used for output projection) ----------------
template<int NX>
__global__ __launch_bounds__(256) void gemm128(const unsigned short* __restrict__ A,
                                               const unsigned short* __restrict__ Bm,
                                               float* __restrict__ o0){
  constexpr int K = 1024;
  constexpr int NWG = NX * 64;
  __shared__ __align__(16) unsigned short As[128*64];
  __shared__ __align__(16) unsigned short Bs[128*64];
  const int tid = threadIdx.x;
  const int flat = blockIdx.y * NX + blockIdx.x;
  const int swz = (flat & 7) * (NWG / 8) + (flat >> 3);
  const int n0 = (swz % NX) * 128;
  const int m0 = (swz / NX) * 128;
  const int w = tid >> 6, lane = tid & 63, l15 = lane & 15, g = lane >> 4;
  const int wm = (w >> 1) * 64, wn = (w & 1) * 64;

  f32x4 acc[4][4] = {};

  for (int k0 = 0; k0 < K; k0 += 64){
    #pragma unroll
    for (int i = 0; i < 4; ++i){
      const int p = i*256 + tid;
      const int r = p >> 3, c = p & 7;
      const int gc = c ^ (r & 7);
      __builtin_amdgcn_global_load_lds(
        (const __attribute__((address_space(1))) void*)(A + (size_t)(m0 + r)*K + k0 + gc*8),
        (__attribute__((address_space(3))) void*)(As + p*8), 16, 0, 0);
    }
    #pragma unroll
    for (int i = 0; i < 4; ++i){
      const int p = i*256 + tid;
      const int r = p >> 3, c = p & 7;
      const int gc = c ^ (r & 7);
      __builtin_amdgcn_global_load_lds(
        (const __attribute__((address_space(1))) void*)(Bm + (size_t)(n0 + r)*K + k0 + gc*8),
        (__attribute__((address_space(3))) void*)(Bs + p*8), 16, 0, 0);
    }
    __syncthreads();

    bf16x8 af[2][4], bfr[2][4];
    #pragma unroll
    for (int ks = 0; ks < 2; ++ks){
      #pragma unroll
      for (int m = 0; m < 4; ++m){
        const int R = wm + m*16 + l15;
        const int c = (ks*4 + g) ^ (R & 7);
        af[ks][m] = as_bf(*(const u16x8*)(As + R*64 + c*8));
      }
      #pragma unroll
      for (int n = 0; n < 4; ++n){
        const int R = wn + n*16 + l15;
        const int c = (ks*4 + g) ^ (R & 7);
        bfr[ks][n] = as_bf(*(const u16x8*)(Bs + R*64 + c*8));
      }
    }
    #pragma unroll
    for (int ks = 0; ks < 2; ++ks)
      #pragma unroll
      for (int m = 0; m < 4; ++m)
        #pragma unroll
        for (int n = 0; n < 4; ++n)
          acc[m][n] = __builtin_amdgcn_mfma_f32_16x16x32_bf16(af[ks][m], bfr[ks][n], acc[m][n], 0, 0, 0);
    __syncthreads();
  }

  #pragma unroll
  for (int m = 0; m < 4; ++m)
    #pragma unroll
    for (int n = 0; n < 4; ++n)
      #pragma unroll
      for (int r = 0; r < 4; ++r){
        const int row = m0 + wm + m*16 + g*4 + r;
        const int col = n0 + wn + n*16 + l15;
        o0[(size_t)row*1024 + col] = acc[m][n][r];
      }
}

// Causal flash attention, swapped-QK 32x32, 8 waves x 32 q-rows = 256 q-rows/block.
// R6-proven: 3-buffer ring, counted vmcnt(2), balanced strip pairing.
__global__ __launch_bounds__(512, 4) void attn2(const unsigned short* __restrict__ Q,
                                                const unsigned short* __restrict__ Km,
                                                const unsigned short* __restrict__ Vt,
                                                unsigned short* __restrict__ Y){
  __shared__ __align__(16) unsigned short Ks[3][64*64];
  __shared__ __align__(16) unsigned short Vs[3][64*64];
  const int bh = blockIdx.x, b = bh >> 4, h = bh & 15;
  const int yq = blockIdx.y;
  const int qt = (yq < 4) ? (7 - yq) : (yq - 4);
  const int tid = threadIdx.x;
  const int w = tid >> 6, lane = tid & 63, l31 = lane & 31, hi = lane >> 5;
  const int q0 = qt * 256;
  const int wq0 = q0 + w * 32;
  const int wqmax = wq0 + 31;
  const int nkt = 4 * qt + 4;
  const int qg = wq0 + l31;

  const unsigned short* Ksrc = Km + (size_t)b*TT*CC + h*DD;
  const unsigned short* Vsrc = Vt + (size_t)bh*DD*TT;

  auto stage = [&](int buf, int kt){
    const int r = tid >> 3, c = tid & 7;
    const int gc = c ^ (r & 7);
    __builtin_amdgcn_global_load_lds(
      (const __attribute__((address_space(1))) void*)(Ksrc + (size_t)(kt*64 + r)*CC + gc*8),
      (__attribute__((address_space(3))) void*)(&Ks[buf][tid*8]), 16, 0, 0);
    __builtin_amdgcn_global_load_lds(
      (const __attribute__((address_space(1))) void*)(Vsrc + (size_t)r*TT + (size_t)kt*64 + c*8),
      (__attribute__((address_space(3))) void*)(&Vs[buf][tid*8]), 16, 0, 0);
  };

  stage(0, 0);

  const unsigned short* qrow = Q + ((size_t)b*TT + wq0 + l31)*CC + h*DD;
  bf16x8 qf[4];
  #pragma unroll
  for (int ds = 0; ds < 4; ++ds)
    qf[ds] = as_bf(*(const u16x8*)(qrow + 16*ds + 8*hi));

  int koff[4];
  #pragma unroll
  for (int ds = 0; ds < 4; ++ds)
    koff[ds] = l31*64 + (((2*ds + hi) ^ (l31 & 7)) * 8);

  float m_ = -1e30f, l_ = 0.f;
  f32x16 y0 = {}, y1 = {};

  int cb = 0;
  for (int t = 0; t < nkt; ++t){
    const int nx = (cb == 2) ? 0 : cb + 1;
    if (t + 1 < nkt){
      stage(nx, t + 1);
      asm volatile("s_waitcnt vmcnt(2)" ::: "memory");
    } else {
      asm volatile("s_waitcnt vmcnt(0)" ::: "memory");
    }
    __builtin_amdgcn_s_barrier();

    if (t*64 <= wqmax){
      const unsigned short* Kp = &Ks[cb][0];
      const unsigned short* Vp = &Vs[cb][0];

      f32x16 s0 = {}, s1 = {};
      __builtin_amdgcn_s_setprio(1);
      #pragma unroll
      for (int ds = 0; ds < 4; ++ds){
        bf16x8 kf0 = as_bf(*(const u16x8*)(Kp + koff[ds]));
        s0 = __builtin_amdgcn_mfma_f32_32x32x16_bf16(kf0, qf[ds], s0, 0, 0, 0);
        bf16x8 kf1 = as_bf(*(const u16x8*)(Kp + koff[ds] + 2048));
        s1 = __builtin_amdgcn_mfma_f32_32x32x16_bf16(kf1, qf[ds], s1, 0, 0, 0);
      }
      __builtin_amdgcn_s_setprio(0);

      if (t*64 + 63 > wq0){
        const int kb0 = t*64;
        #pragma unroll
        for (int r = 0; r < 16; ++r){
          const int kr = (r & 3) + 8*(r >> 2) + 4*hi;
          if (kb0 + kr      > qg) s0[r] = -1e30f;
          if (kb0 + 32 + kr > qg) s1[r] = -1e30f;
        }
      }

      float tm[8];
      #pragma unroll
      for (int r = 0; r < 8; ++r) tm[r] = fmaxf(fmaxf(s0[r], s0[r+8]), fmaxf(s1[r], s1[r+8]));
      #pragma unroll
      for (int r = 0; r < 4; ++r) tm[r] = fmaxf(tm[r], tm[r+4]);
      float pmax = fmaxf(fmaxf(tm[0], tm[2]), fmaxf(tm[1], tm[3]));
      pmax = fmaxf(pmax, __shfl_xor(pmax, 32));

      if (!__all(pmax <= m_ + 8.f)){
        const float mnew = fmaxf(m_, pmax);
        const float alpha = ex2(m_ - mnew);
        l_ *= alpha;
        #pragma unroll
        for (int r = 0; r < 16; ++r){
          const float ar = __shfl(alpha, (r & 3) + 8*(r >> 2) + 4*hi);
          y0[r] *= ar; y1[r] *= ar;
        }
        m_ = mnew;
      }

      #pragma unroll
      for (int r = 0; r < 16; ++r) s0[r] = ex2(s0[r] - m_);
      #pragma unroll
      for (int r = 0; r < 16; ++r) s1[r] = ex2(s1[r] - m_);
      float ts[8];
      #pragma unroll
      for (int r = 0; r < 8; ++r) ts[r] = (s0[r] + s0[r+8]) + (s1[r] + s1[r+8]);
      #pragma unroll
      for (int r = 0; r < 4; ++r) ts[r] += ts[r+4];
      float rs = (ts[0] + ts[2]) + (ts[1] + ts[3]);
      rs += __shfl_xor(rs, 32);
      l_ += rs;

      __builtin_amdgcn_s_setprio(1);
      #pragma unroll
      for (int m = 0; m < 4; ++m){
        const f32x16 c = (m < 2) ? s0 : s1;
        const int bx = (m & 1) * 8;
        unsigned A0 = cvt_pk(c[bx+0], c[bx+1]);
        unsigned B0 = cvt_pk(c[bx+4], c[bx+5]);
        pl32swap(A0, B0);
        unsigned A1 = cvt_pk(c[bx+2], c[bx+3]);
        unsigned B1 = cvt_pk(c[bx+6], c[bx+7]);
        pl32swap(A1, B1);
        u32x4 pw; pw.x = A0; pw.y = A1; pw.z = B0; pw.w = B1;
        const bf16x8 pa = __builtin_bit_cast(bf16x8, pw);
        bf16x8 vf0 = as_bf(*(const u16x8*)(Vp + koff[m]));
        y0 = __builtin_amdgcn_mfma_f32_32x32x16_bf16(pa, vf0, y0, 0, 0, 0);
        bf16x8 vf1 = as_bf(*(const u16x8*)(Vp + koff[m] + 2048));
        y1 = __builtin_amdgcn_mfma_f32_32x32x16_bf16(pa, vf1, y1, 0, 0, 0);
      }
      __builtin_amdgcn_s_setprio(0);
    }
    cb = nx;
  }

  const float linv = 1.f / l_;
  #pragma unroll
  for (int r = 0; r < 16; ++r){
    const int qlr = (r & 3) + 8*(r >> 2) + 4*hi;
    const float lr = __shfl(linv, qlr);
    unsigned short* yp = Y + ((size_t)b*TT + wq0 + qlr)*CC + h*DD + l31;
    yp[0]  = f2bf(y0[r] * lr);
    yp[32] = f2bf(y1[r] * lr);
  }
}

extern "C" void kernel_launch(void* const* d_in, const int* in_sizes, int n_in,
                              void* d_out, int out_size, void* d_ws, size_t ws_size,
                              hipStream_t stream){
  const float* x  = (const float*)d_in[0];
  const float* Wk = (const float*)d_in[1];
  const float* Wq = (const float*)d_in[2];
  const float* Wv = (const float*)d_in[3];
  const float* Wp = (const float*)d_in[4];

  const size_t E  = (size_t)BB*TT*CC;
  const size_t Wn = (size_t)CC*CC;
  unsigned short* ws  = (unsigned short*)d_ws;
  unsigned short* xb  = ws;                 // reused as yb after attention
  unsigned short* wkb = xb  + E;            // wkb,wqb,wvb contiguous = B[3072][1024]
  unsigned short* wqb = wkb + Wn;
  unsigned short* wvb = wqb + Wn;
  unsigned short* wpb = wvb + Wn;
  unsigned short* qb  = wpb + Wn;
  unsigned short* kb  = qb  + E;
  unsigned short* vt  = kb  + E;            // V written transposed by QKV GEMM

  (void)wqb; (void)wvb;

  hipFuncSetAttribute(reinterpret_cast<const void*>(gemm256q<12>),
                      hipFuncAttributeMaxDynamicSharedMemorySize, 163840);

  cvt_all<<<12288, 256, 0, stream>>>(x, Wk, Wq, Wv, Wp, xb, wkb);

  // fused QKV at 256^2: B = [Wk; Wq; Wv] -> kb, qb (scaled), vt (transposed+swizzled)
  gemm256q<12><<<dim3(12, 32), 512, 163840, stream>>>(xb, wkb, kb, qb, vt);

  unsigned short* yb = xb;
  attn2<<<dim3(BB*HH, TT/256), 512, 0, stream>>>(qb, kb, vt, yb);

  gemm128<8><<<dim3(8, 64), 256, 0, stream>>>(yb, wpb, (float*)d_out);
}